// Round 15
// baseline (259.830 us; speedup 1.0000x reference)
//
#include <hip/hip_runtime.h>
#include <hip/hip_bf16.h>

typedef __attribute__((ext_vector_type(8))) short short8;
typedef __attribute__((ext_vector_type(4))) float f32x4;
typedef __attribute__((ext_vector_type(4))) float float4v;
typedef __attribute__((ext_vector_type(8))) unsigned short ushort8;

// RNE float -> bf16 payload
__device__ __forceinline__ unsigned short f2bf(float f) {
    union { float f; unsigned u; } x; x.f = f;
    unsigned r = x.u + 0x7FFFu + ((x.u >> 16) & 1u);
    return (unsigned short)(r >> 16);
}

// C[k][n] = s(k) * cos(pi * k * (2n+1) / (2N)), N = 512, ortho norm.
__global__ __launch_bounds__(256) void make_dct_mat(unsigned short* __restrict__ Cm) {
    int idx = blockIdx.x * 256 + threadIdx.x;
    int k = idx >> 9;
    int n = idx & 511;
    int m = (k * (2 * n + 1)) & 2047;             // mod 4N
    float ang = (3.14159265358979323846f / 1024.0f) * (float)m;
    float s = (k == 0) ? 0.04419417382415922f : 0.0625f;
    Cm[idx] = f2bf(s * cosf(ang));
}

#define GLD16(g, l) __builtin_amdgcn_global_load_lds( \
    (const __attribute__((address_space(1))) void*)(g), \
    (__attribute__((address_space(3))) void*)(l), 16, 0, 0)
#define BAR()    asm volatile("s_barrier" ::: "memory")
#define VMCNT(n) asm volatile("s_waitcnt vmcnt(" #n ")" ::: "memory")
#define LGKM0()  asm volatile("s_waitcnt lgkmcnt(0)" ::: "memory")
#define MEMORD() asm volatile("" ::: "memory")

// ============================ STAGE 1 =======================================
// V[img] = C * X[img]^T.  BM=512 (all C rows, L2-hot) x BN=128 strip, BK=32.
// 8 waves (4M x 2N), wave tile 128x64, acc 8x4. 16 K-tiles.
// 3-slot LDS ring for BOTH operands (A bf16 96 KB + B fp32 48 KB = 144 KB):
// prefetch distance = 2 FULL TILES (~2x HBM latency), 6 GLD16/tile,
// counted VMCNT(6) (never 0 mid-loop), ONE barrier per tile.
// B is staged as RAW FP32 via global_load_lds and converted to bf16 on the
// read side (2 float4 + 4 cvt_pk per fragment) -> no reg ledger, no spill.
// LDS swizzles: A = proven ((t&3)^((t>>3)&3)); B fp32 [128][32] uses
// slotL = slotG ^ (row&7): 8 lanes/bank-quad with distinct rows = structural
// minimum for ds_read_b128, zero extra conflicts.
__global__ __launch_bounds__(512, 2) void dct_gemm_s1(
    const unsigned short* __restrict__ A, const float* __restrict__ B,
    unsigned short* __restrict__ D)
{
    __shared__ unsigned short As[3][4][128 * 32];   // 96 KB
    __shared__ float          Bf[3][128 * 32];      // 48 KB

    // XCD-bijective swizzle (1024 % 8 == 0).
    int wg  = blockIdx.x;
    int cpx = gridDim.x >> 3;
    int swz = (wg & 7) * cpx + (wg >> 3);
    int img = swz >> 2;
    int C0  = (swz & 3) * 128;

    int t    = threadIdx.x;        // 0..511
    int lane = t & 63;
    int wid  = t >> 6;             // 0..7
    int wm   = wid >> 1;           // 0..3 -> rows [wm*128,+128)
    int wn   = wid & 1;            // 0..1 -> cols [C0+wn*64,+64)
    int l15  = lane & 15;
    int q    = lane >> 4;          // 0..3 k-slot group

    const size_t imgoff = (size_t)img * (512 * 512);

    // A staging: 4 msubs [128][32] bf16; thread t -> (row=t>>2, slotL=t&3).
    const int aslotG = ((t & 3) ^ ((t >> 3) & 3)) * 8;
    const unsigned short* gA = A + (size_t)(t >> 2) * 512 + aslotG;
    // B staging: [128][32] fp32; thread t -> (row=t>>3, slotL=t&7), 2 ops.
    const int bslotG = ((t & 7) ^ ((t >> 3) & 7)) * 4;   // float offset
    const float* gB = B + imgoff + (size_t)(C0 + (t >> 3)) * 512 + bslotG;

    auto stage = [&](int sl, int kt) {   // 6 GLD16 / thread
        #pragma unroll
        for (int ms = 0; ms < 4; ++ms)
            GLD16(gA + (size_t)ms * 128 * 512 + kt * 32, &As[sl][ms][t * 8]);
        GLD16(gB + kt * 32,                     &Bf[sl][t * 4]);
        GLD16(gB + kt * 32 + (size_t)64 * 512,  &Bf[sl][2048 + t * 4]);
    };

    const int aroff = ((lane >> 4) ^ ((lane >> 1) & 3)) * 8;  // proven A read swz
    const int bs0 = ((2 * q)     ^ (lane & 7)) * 4;           // fp32 read swz
    const int bs1 = ((2 * q + 1) ^ (lane & 7)) * 4;           // (row&7 == lane&7)

    f32x4 acc[8][4] = {};

    // ---- prologue: tiles 0,1 in flight; retire tile0, keep tile1 ----
    stage(0, 0);
    stage(1, 1);
    VMCNT(6);
    BAR();

    // ---- main loop: one barrier/tile, distance-2 ring ----
    #pragma unroll 4
    for (int kt = 0; kt < 16; ++kt) {
        const int sl = kt % 3;
        if (kt < 14) stage((kt + 2) % 3, kt + 2);

        short8 av[8], bv[4];
        #pragma unroll
        for (int m = 0; m < 8; ++m)
            av[m] = *(const short8*)(&As[sl][wm][(m * 16 + l15) * 32 + aroff]);
        #pragma unroll
        for (int n = 0; n < 4; ++n) {
            int brow = wn * 64 + n * 16 + l15;
            float4v fa = *(const float4v*)(&Bf[sl][brow * 32 + bs0]);
            float4v fb = *(const float4v*)(&Bf[sl][brow * 32 + bs1]);
            union { short8 s8; __hip_bfloat162 h2[4]; } u;
            u.h2[0] = __float22bfloat162_rn(float2{fa.x, fa.y});
            u.h2[1] = __float22bfloat162_rn(float2{fa.z, fa.w});
            u.h2[2] = __float22bfloat162_rn(float2{fb.x, fb.y});
            u.h2[3] = __float22bfloat162_rn(float2{fb.z, fb.w});
            bv[n] = u.s8;
        }
        __builtin_amdgcn_s_setprio(1);
        #pragma unroll
        for (int m = 0; m < 8; ++m)
            #pragma unroll
            for (int n = 0; n < 4; ++n)
                acc[m][n] = __builtin_amdgcn_mfma_f32_16x16x32_bf16(
                                av[m], bv[n], acc[m][n], 0, 0, 0);
        __builtin_amdgcn_s_setprio(0);

        if (kt < 14)      { VMCNT(6); BAR(); }   // retire stage(kt+1); keep kt+2
        else if (kt == 14){ VMCNT(0); BAR(); }   // tail: ensure stage(15) landed
    }

    // ---- epilogue: col = lane&15, row = (lane>>4)*4 + reg ----
    unsigned short* Dp = D + imgoff;
    int r0 = wm * 128 + q * 4;
    int c0 = C0 + wn * 64 + l15;
    #pragma unroll
    for (int m = 0; m < 8; ++m)
        #pragma unroll
        for (int n = 0; n < 4; ++n)
            #pragma unroll
            for (int r = 0; r < 4; ++r)
                Dp[(size_t)(r0 + m * 16 + r) * 512 + c0 + n * 16] = f2bf(acc[m][n][r]);
}

// ============================ STAGE 2 =======================================
// Unchanged R14 structure (proven ~85 us): BM=BN=256, BK=64, 8-phase,
// counted vmcnt, pure global_load_lds bf16, proven zero-conflict layout.
__global__ __launch_bounds__(512, 2) void dct_gemm_s2(
    const unsigned short* __restrict__ A, const unsigned short* __restrict__ B,
    float* __restrict__ D)
{
    __shared__ unsigned short As[2][2][2][4096];
    __shared__ unsigned short Bs[2][2][2][4096];

    int wg  = blockIdx.x;
    int cpx = gridDim.x >> 3;
    int swz = (wg & 7) * cpx + (wg >> 3);
    int img = swz >> 2;
    int R0  = ((swz >> 1) & 1) * 256;
    int C0  = (swz & 1) * 256;

    int t    = threadIdx.x;
    int lane = t & 63;
    int wid  = t >> 6;
    int wm   = wid >> 2;
    int wn   = wid & 3;
    int l15  = lane & 15;
    const int roff = ((lane >> 4) ^ ((lane >> 1) & 3)) * 8;

    const size_t imgoff = (size_t)img * (512 * 512);

    const int sXor = ((t & 3) ^ ((t >> 3) & 3)) * 8;
    const unsigned short* gA = A
        + (size_t)(R0 + (t >> 8) * 128 + ((t >> 2) & 63)) * 512 + sXor;
    const int bRow = C0 + ((t >> 7) & 3) * 64 + ((t >> 2) & 31);
    const unsigned short* gB16 =
        B + imgoff + (size_t)bRow * 512 + sXor;

    auto stageA = [&](int d, int kt, int h) {
        GLD16(gA + (size_t)h * 64 * 512 + kt * 64,      &As[d][h][0][t * 8]);
        GLD16(gA + (size_t)h * 64 * 512 + kt * 64 + 32, &As[d][h][1][t * 8]);
    };
    auto stageB = [&](int d, int kt, int h) {
        GLD16(gB16 + (size_t)h * 32 * 512 + kt * 64,      &Bs[d][h][0][t * 8]);
        GLD16(gB16 + (size_t)h * 32 * 512 + kt * 64 + 32, &Bs[d][h][1][t * 8]);
    };

    short8 avA[4][2], avB[4][2], bvA[2][2], bvB[2][2];
    auto readA = [&](short8 av[4][2], int d, int mh) {
        #pragma unroll
        for (int mq = 0; mq < 4; ++mq)
            #pragma unroll
            for (int ks = 0; ks < 2; ++ks)
                av[mq][ks] = *(const short8*)(
                    &As[d][mh][ks][(wm * 64 + mq * 16 + l15) * 32 + roff]);
    };
    auto readB = [&](short8 bv[2][2], int d, int nh) {
        #pragma unroll
        for (int nq = 0; nq < 2; ++nq)
            #pragma unroll
            for (int ks = 0; ks < 2; ++ks)
                bv[nq][ks] = *(const short8*)(
                    &Bs[d][nh][ks][(wn * 32 + nq * 16 + l15) * 32 + roff]);
    };

    f32x4 acc[8][4] = {};
    auto mfmaQ = [&](short8 av[4][2], short8 bv[2][2], int mh, int nh) {
        __builtin_amdgcn_s_setprio(1);
        #pragma unroll
        for (int mq = 0; mq < 4; ++mq)
            #pragma unroll
            for (int nq = 0; nq < 2; ++nq)
                #pragma unroll
                for (int ks = 0; ks < 2; ++ks)
                    acc[mh*4+mq][nh*2+nq] = __builtin_amdgcn_mfma_f32_16x16x32_bf16(
                        av[mq][ks], bv[nq][ks], acc[mh*4+mq][nh*2+nq], 0, 0, 0);
        __builtin_amdgcn_s_setprio(0);
    };

    stageA(0, 0, 0); MEMORD(); stageB(0, 0, 0); MEMORD();
    stageB(0, 0, 1); MEMORD(); stageA(0, 0, 1);
    VMCNT(4);
    BAR();

    #pragma unroll
    for (int kt = 0; kt < 8; ++kt) {
        const int d = kt & 1, e = d ^ 1;
        // P0
        readA(avA, d, 0); readB(bvA, d, 0);
        if (kt < 7) { stageA(e, kt + 1, 0); VMCNT(4); }
        else        { VMCNT(2); }
        BAR(); LGKM0();
        mfmaQ(avA, bvA, 0, 0);
        BAR();
        // P1
        readB(bvB, d, 1);
        if (kt < 7) { stageB(e, kt + 1, 0); VMCNT(4); }
        else        { VMCNT(0); }
        BAR(); LGKM0();
        mfmaQ(avA, bvB, 0, 1);
        BAR();
        // P2
        readA(avB, d, 1);
        if (kt < 7) { stageB(e, kt + 1, 1); VMCNT(4); }
        BAR(); LGKM0();
        mfmaQ(avB, bvB, 1, 1);
        BAR();
        // P3
        if (kt < 7) { stageA(e, kt + 1, 1); VMCNT(4); }
        BAR(); LGKM0();
        mfmaQ(avB, bvA, 1, 0);
        BAR();
    }

    float* Dp = D + imgoff;
    int r0 = R0 + wm * 128 + (lane >> 4) * 4;
    int c0 = C0 + wn * 64 + l15;
    #pragma unroll
    for (int m = 0; m < 8; ++m)
        #pragma unroll
        for (int n = 0; n < 4; ++n)
            #pragma unroll
            for (int r = 0; r < 4; ++r)
                Dp[(size_t)(r0 + (m >> 2) * 64 + (m & 3) * 16 + r) * 512
                   + c0 + (n >> 1) * 32 + (n & 1) * 16] = acc[m][n][r];
}

extern "C" void kernel_launch(void* const* d_in, const int* in_sizes, int n_in,
                              void* d_out, int out_size, void* d_ws, size_t ws_size,
                              hipStream_t stream) {
    const float* x = (const float*)d_in[0];
    float* out = (float*)d_out;

    // ws layout: [0, 512KB) = C matrix bf16; [1MB, 1MB+128MB) = intermediate V bf16
    unsigned short* Cm = (unsigned short*)d_ws;
    unsigned short* Tm = (unsigned short*)((char*)d_ws + (1 << 20));

    int nimg = in_sizes[0] / (512 * 512);   // 256

    make_dct_mat<<<dim3(1024), dim3(256), 0, stream>>>(Cm);
    // Stage 1: V[b] = C * X[b]^T   (B = raw fp32 via global_load_lds, cvt on read)
    dct_gemm_s1<<<dim3(nimg * 4), dim3(512), 0, stream>>>(Cm, x, Tm);
    // Stage 2: Y[b] = C * V[b]^T = C X C^T  (B = bf16 via global_load_lds)
    dct_gemm_s2<<<dim3(nimg * 4), dim3(512), 0, stream>>>(Cm, Tm, out);
}